// Round 1
// baseline (242.260 us; speedup 1.0000x reference)
//
#include <hip/hip_runtime.h>
#include <hip/hip_bf16.h>

#define BB 4
#define TT 4096
#define CC 1024
#define HH 64

typedef _Float16 f16;
typedef __attribute__((ext_vector_type(8))) _Float16 f16x8;
typedef __attribute__((ext_vector_type(4))) _Float16 f16x4;
typedef __attribute__((ext_vector_type(4))) float f32x4;

#define MFMA32(a,b,c) __builtin_amdgcn_mfma_f32_16x16x32_f16((a),(b),(c),0,0,0)
#define MFMA16(a,b,c) __builtin_amdgcn_mfma_f32_16x16x16f16((a),(b),(c),0,0,0)

// frag-major sizes (f16 units)
#define WF_ELEMS (3 * 32 * 4 * 64 * 8)        // 196,608
#define CHUNK_F16 1024                        // per 16-row chunk: 2 halves x 64 lanes x 8
#define PB_F16 (256 * CHUNK_F16)              // per batch: 256 chunks

// Async global->LDS, 16B per lane. Side-effecting: compiler cannot sink it.
// LDS dest must be wave-uniform; lane i's 16B lands at dest + i*16.
static __device__ __forceinline__ void gl_lds16(const void* g, void* l) {
  __builtin_amdgcn_global_load_lds(
      (const __attribute__((address_space(1))) unsigned int*)g,
      (__attribute__((address_space(3))) unsigned int*)l, 16, 0, 0);
}

static __device__ __forceinline__ f16x8 pack2(f32x4 a, f32x4 b) {
  f16x8 r;
  r[0]=(f16)a[0]; r[1]=(f16)a[1]; r[2]=(f16)a[2]; r[3]=(f16)a[3];
  r[4]=(f16)b[0]; r[5]=(f16)b[1]; r[6]=(f16)b[2]; r[7]=(f16)b[3];
  return r;
}

// ---------------------------------------------------------------------------
// Repack W -> frag-major f16. Block bx = (p*32+kc)*4+nt, 64 threads.
// Softmax double-scale log2(e)/64 folded into Wq.
// ---------------------------------------------------------------------------
__global__ __launch_bounds__(64) void wrepack_kernel(
    const float* __restrict__ Wqg, const float* __restrict__ Wkg,
    const float* __restrict__ Wvg, f16* __restrict__ Wf)
{
  const int bx = blockIdx.x;
  const int nt = bx & 3;
  const int kc = (bx >> 2) & 31;
  const int p  = bx >> 7;
  const float* W = (p == 0) ? Wqg : (p == 1) ? Wkg : Wvg;
  const float sc = (p == 0) ? (1.4426950408889634f / 64.0f) : 1.0f;

  const int lane = threadIdx.x;
  const int l16 = lane & 15, quad = lane >> 4;
  const float* src = W + (size_t)(nt * 16 + l16) * CC + kc * 32 + quad * 8;
  f32x4 a = *(const f32x4*)src;
  f32x4 b = *(const f32x4*)(src + 4);
  f16x8 r;
  #pragma unroll
  for (int j = 0; j < 4; ++j) { r[j] = (f16)(a[j] * sc); r[j + 4] = (f16)(b[j] * sc); }
  *(f16x8*)(Wf + (size_t)bx * 512 + lane * 8) = r;
}

// ---------------------------------------------------------------------------
// Projection: X[16384,1024] fp32 x W^T -> frag-major f16.
// Barrier-free streaming version. The A-fragment of mfma_f32_16x16x32_f16 is
// lane(row=l16, cols=quad*8+j): read DIRECTLY from global — a wave's two
// f32x4 loads cover 16 rows x 128B contiguous (100% line utilization), so LDS
// staging buys nothing. W fragments are frag-major in Wf: each wave reads a
// contiguous 1KB chunk shared by all blocks -> L2-hot. No __syncthreads ->
// no vmcnt(0) drains -> the fully-unrolled K loop keeps many 1KB/wave loads
// in flight (the old 2-buffer staging loop drained to vmcnt(0) every 24KB,
// capping proj at 1.4 TB/s / 17% of HBM peak).
// Small wave-private LDS scratch only for the frag-major epilogue transpose.
// ---------------------------------------------------------------------------
__global__ __launch_bounds__(256) void proj_kernel(
    const float* __restrict__ qg, const float* __restrict__ kg, const float* __restrict__ vg,
    const f16* __restrict__ Wf,
    f16* __restrict__ Qf, f16* __restrict__ Kf, f16* __restrict__ Vf)
{
  __shared__ f16 Lsw[4][16][66];   // per-wave transpose scratch, 8.25 KB

  const float* X; f16* O; const int p = blockIdx.y;
  if (p == 0)      { X = qg; O = Qf; }
  else if (p == 1) { X = kg; O = Kf; }
  else             { X = vg; O = Vf; }

  const int tid  = threadIdx.x;
  const int w    = tid >> 6;
  const int lane = tid & 63;
  const int quad = lane >> 4;
  const int l16  = lane & 15;
  const int r0   = blockIdx.x * 64 + w * 16;   // wave's 16-row tile

  // lane's A source: row r0+l16, k-offset quad*8 within each 32-chunk
  const float* xrow = X + (size_t)(r0 + l16) * CC + quad * 8;
  // lane's B source: frag-major W, 16B per lane, contiguous 1KB per wave-read
  const f16* wbase = Wf + (size_t)p * 128 * 512 + lane * 8;

  f32x4 acc[4];
  #pragma unroll
  for (int nt = 0; nt < 4; ++nt) acc[nt] = (f32x4){0.f, 0.f, 0.f, 0.f};

  #pragma unroll
  for (int kc = 0; kc < 32; ++kc) {
    f32x4 a0 = *(const f32x4*)(xrow + kc * 32);
    f32x4 a1 = *(const f32x4*)(xrow + kc * 32 + 4);
    f16x8 af = pack2(a0, a1);
    #pragma unroll
    for (int nt = 0; nt < 4; ++nt) {
      f16x8 bf = *(const f16x8*)(wbase + ((size_t)kc * 4 + nt) * 512);
      acc[nt] = MFMA32(af, bf, acc[nt]);
    }
  }

  // epilogue: C-layout acc -> frag-major via wave-private LDS scratch.
  // Same-wave ds_write -> ds_read: compiler orders via lgkmcnt; no barrier.
  f16 (*Ls)[66] = Lsw[w];
  #pragma unroll
  for (int nt = 0; nt < 4; ++nt)
    #pragma unroll
    for (int r = 0; r < 4; ++r)
      Ls[quad * 4 + r][nt * 16 + l16] = (f16)acc[nt][r];
  const size_t chunk = (size_t)blockIdx.x * 4 + w;
  if (p < 2) {
    // Q/K frag: [chunk][half][lane][8] = tile[row=l16][hd=32h+8q+j]
    #pragma unroll
    for (int h = 0; h < 2; ++h) {
      f16x8 t = *(const f16x8*)&Ls[l16][h * 32 + quad * 8];
      *(f16x8*)(O + (chunk * 2 + h) * 512 + lane * 8) = t;
    }
  } else {
    // V frag: [chunk][np][lane][8] = tile[key=4q+(j&3)][hd=(2np+(j>>2))*16+l16]
    #pragma unroll
    for (int np = 0; np < 2; ++np) {
      f16x8 t;
      #pragma unroll
      for (int j = 0; j < 8; ++j)
        t[j] = Ls[quad * 4 + (j & 3)][(2 * np + (j >> 2)) * 16 + l16];
      *(f16x8*)(O + (chunk * 2 + np) * 512 + lane * 8) = t;
    }
  }
}

// ---------------------------------------------------------------------------
// Flash attention, mask s <= t+1. Block-wide double-buffered async staging of
// K and V steps (each step = contiguous 8 KB in frag-major layout). Frag reads
// are lane-linear ds_read_b128 (conflict-free). Uniform trip counts.
// S^T via MFMA(A=K,B=Q); P C-layout == MFMA16 A-layout. Scale folded into Wq.
// ---------------------------------------------------------------------------
__device__ __forceinline__ void attn_tile(
    int b, int j, int a, int e, int wave, int quad, int l16, int lane, int sp,
    const f16* __restrict__ Qf, const f16* __restrict__ Kf, const f16* __restrict__ Vf,
    f16 (*Ks)[8][64][8], f16 (*Vs)[8][64][8],
    float* __restrict__ Opart, float* __restrict__ lpart)
{
  const int m0 = j * 64 + wave * 16;

  const f16* Kfb = Kf + (size_t)b * PB_F16;
  const f16* Vfb = Vf + (size_t)b * PB_F16;
  const f16* Qfb = Qf + (size_t)b * PB_F16;

  f16x8 qa0 = *(const f16x8*)(Qfb + ((size_t)(m0 >> 4) * 2 + 0) * 512 + lane * 8);
  f16x8 qa1 = *(const f16x8*)(Qfb + ((size_t)(m0 >> 4) * 2 + 1) * 512 + lane * 8);

  f32x4 o[4];
  float lsum = 0.f;
  #pragma unroll
  for (int nt = 0; nt < 4; ++nt) o[nt] = (f32x4){0.f, 0.f, 0.f, 0.f};

  // protect staging buffers from the previous tile's laggard readers
  __syncthreads();

  if (a < e) {
    #pragma unroll
    for (int jj = 0; jj < 2; ++jj) {
      const int idx = 2 * wave + jj;
      gl_lds16(Kfb + (size_t)a * 4096 + idx * 512 + lane * 8, &Ks[0][idx][0][0]);
      gl_lds16(Vfb + (size_t)a * 4096 + idx * 512 + lane * 8, &Vs[0][idx][0][0]);
    }
  }

  for (int st = a; st < e; ++st) {
    const int buf = (st - a) & 1;
    __syncthreads();   // drains staging of buf
    if (st + 1 < e) {
      #pragma unroll
      for (int jj = 0; jj < 2; ++jj) {
        const int idx = 2 * wave + jj;
        gl_lds16(Kfb + (size_t)(st + 1) * 4096 + idx * 512 + lane * 8, &Ks[buf ^ 1][idx][0][0]);
        gl_lds16(Vfb + (size_t)(st + 1) * 4096 + idx * 512 + lane * 8, &Vs[buf ^ 1][idx][0][0]);
      }
    }
    const int s0 = st * 64;

    // S^T = K Q^T (scale pre-folded into Q)
    f32x4 sc[4];
    #pragma unroll
    for (int ct = 0; ct < 4; ++ct) {
      f16x8 k0 = *(const f16x8*)&Ks[buf][ct * 2][lane][0];
      f16x8 k1 = *(const f16x8*)&Ks[buf][ct * 2 + 1][lane][0];
      f32x4 z = (f32x4){0.f, 0.f, 0.f, 0.f};
      z = MFMA32(k0, qa0, z);
      sc[ct] = MFMA32(k1, qa1, z);
    }

    // mask + exp2; lane: query=m0+l16, key=s0+ct*16+quad*4+r
    const bool domask = (s0 + 63) > (m0 + 1);
    f16x4 pa[4];
    #pragma unroll
    for (int ct = 0; ct < 4; ++ct) {
      #pragma unroll
      for (int r = 0; r < 4; ++r) {
        float x = sc[ct][r];
        if (domask) {
          const int key = s0 + ct * 16 + quad * 4 + r;
          if (key > m0 + l16 + 1) x = -__builtin_inff();
        }
        const float pv = __builtin_amdgcn_exp2f(x);
        lsum += pv;
        pa[ct][r] = (f16)pv;
      }
    }

    // PV: A=P (MFMA16 A-layout), B=V frag halves
    #pragma unroll
    for (int ct = 0; ct < 4; ++ct) {
      #pragma unroll
      for (int np = 0; np < 2; ++np) {
        f16x8 vv = *(const f16x8*)&Vs[buf][ct * 2 + np][lane][0];
        f16x4 blo = __builtin_shufflevector(vv, vv, 0, 1, 2, 3);
        f16x4 bhi = __builtin_shufflevector(vv, vv, 4, 5, 6, 7);
        o[2 * np]     = MFMA16(pa[ct], blo, o[2 * np]);
        o[2 * np + 1] = MFMA16(pa[ct], bhi, o[2 * np + 1]);
      }
    }
  }

  lsum += __shfl_xor(lsum, 16, 64);
  lsum += __shfl_xor(lsum, 32, 64);
  const size_t rbase = (size_t)(sp * BB + b) * TT;
  if (quad == 0) lpart[rbase + m0 + l16] = lsum;
  #pragma unroll
  for (int nt = 0; nt < 4; ++nt)
    #pragma unroll
    for (int r = 0; r < 4; ++r)
      Opart[(rbase + m0 + quad * 4 + r) * HH + nt * 16 + l16] = o[nt][r];
}

__global__ __launch_bounds__(256) void attn_kernel(
    const f16* __restrict__ Qf, const f16* __restrict__ Kf, const f16* __restrict__ Vf,
    float* __restrict__ Opart, float* __restrict__ lpart, int S)
{
  __shared__ f16 Ks[2][8][64][8];   // 16 KB
  __shared__ f16 Vs[2][8][64][8];   // 16 KB

  const int pr = blockIdx.x;
  const int sp = blockIdx.y;
  const int b  = blockIdx.z;
  const int tid  = threadIdx.x;
  const int wave = tid >> 6;
  const int lane = tid & 63;
  const int quad = lane >> 4;
  const int l16  = lane & 15;

  const int j1 = pr, j2 = 63 - pr;
  const int n1 = min(j1 + 2, 64), n2 = min(j2 + 2, 64);
  const int tot = n1 + n2;
  const int lo = tot * sp / S, hi = tot * (sp + 1) / S;
  const int a1 = min(lo, n1), e1 = min(hi, n1);
  const int a2 = max(lo - n1, 0), e2 = max(hi - n1, 0);

  attn_tile(b, j1, a1, e1, wave, quad, l16, lane, sp, Qf, Kf, Vf, Ks, Vs, Opart, lpart);
  attn_tile(b, j2, a2, e2, wave, quad, l16, lane, sp, Qf, Kf, Vf, Ks, Vs, Opart, lpart);
}

// ---------------------------------------------------------------------------
// Combine S split partials: out = sum_s O_s / sum_s l_s
// ---------------------------------------------------------------------------
__global__ __launch_bounds__(256) void combine_kernel(
    const float* __restrict__ Opart, const float* __restrict__ lpart,
    float* __restrict__ out, int S)
{
  const int idx = blockIdx.x * 256 + threadIdx.x;
  const int row = idx >> 4;
  const int c   = (idx & 15) * 4;
  float l = 0.f;
  f32x4 s = (f32x4){0.f, 0.f, 0.f, 0.f};
  for (int p = 0; p < S; ++p) {
    l += lpart[(size_t)p * BB * TT + row];
    s += *(const f32x4*)&Opart[((size_t)p * BB * TT + row) * HH + c];
  }
  const float inv = 1.0f / l;
  *(f32x4*)&out[(size_t)row * HH + c] = s * inv;
}

// ---------------------------------------------------------------------------
extern "C" void kernel_launch(void* const* d_in, const int* in_sizes, int n_in,
                              void* d_out, int out_size, void* d_ws, size_t ws_size,
                              hipStream_t stream)
{
  const float* q  = (const float*)d_in[0];
  const float* k  = (const float*)d_in[1];
  const float* v  = (const float*)d_in[2];
  const float* Wq = (const float*)d_in[3];
  const float* Wk = (const float*)d_in[4];
  const float* Wv = (const float*)d_in[5];
  float* out = (float*)d_out;

  const size_t n = (size_t)BB * TT * HH;   // 1,048,576 f16 per tensor
  const size_t need8 = (WF_ELEMS + 3 * n) * sizeof(f16)
                     + 8 * n * sizeof(float) + 8 * (size_t)BB * TT * sizeof(float);
  const int S = (ws_size >= need8) ? 8 : 4;

  f16* Wf = (f16*)d_ws;
  f16* Qf = Wf + WF_ELEMS;
  f16* Kf = Qf + n;
  f16* Vf = Kf + n;
  float* Opart = (float*)(Vf + n);
  float* lpart = Opart + (size_t)S * n;

  wrepack_kernel<<<dim3(384), 64, 0, stream>>>(Wq, Wk, Wv, Wf);
  proj_kernel<<<dim3(256, 3), 256, 0, stream>>>(q, k, v, Wf, Qf, Kf, Vf);
  attn_kernel<<<dim3(32, S, BB), 256, 0, stream>>>(Qf, Kf, Vf, Opart, lpart, S);
  combine_kernel<<<dim3(1024), 256, 0, stream>>>(Opart, lpart, out, S);
}

// Round 2
// 237.851 us; speedup vs baseline: 1.0185x; 1.0185x over previous
//
#include <hip/hip_runtime.h>
#include <hip/hip_bf16.h>

#define BB 4
#define TT 4096
#define CC 1024
#define HH 64

typedef _Float16 f16;
typedef __attribute__((ext_vector_type(8))) _Float16 f16x8;
typedef __attribute__((ext_vector_type(4))) _Float16 f16x4;
typedef __attribute__((ext_vector_type(4))) float f32x4;

#define MFMA32(a,b,c) __builtin_amdgcn_mfma_f32_16x16x32_f16((a),(b),(c),0,0,0)
#define MFMA16(a,b,c) __builtin_amdgcn_mfma_f32_16x16x16f16((a),(b),(c),0,0,0)

// frag-major sizes (f16 units)
#define WF_ELEMS (3 * 32 * 4 * 64 * 8)        // 196,608
#define CHUNK_F16 1024                        // per 16-row chunk: 2 halves x 64 lanes x 8
#define PB_F16 (256 * CHUNK_F16)              // per batch: 256 chunks

// Async global->LDS, 16B per lane. Side-effecting: compiler cannot sink it.
// LDS dest must be wave-uniform; lane i's 16B lands at dest + i*16.
static __device__ __forceinline__ void gl_lds16(const void* g, void* l) {
  __builtin_amdgcn_global_load_lds(
      (const __attribute__((address_space(1))) unsigned int*)g,
      (__attribute__((address_space(3))) unsigned int*)l, 16, 0, 0);
}

static __device__ __forceinline__ f16x8 pack2(f32x4 a, f32x4 b) {
  f16x8 r;
  r[0]=(f16)a[0]; r[1]=(f16)a[1]; r[2]=(f16)a[2]; r[3]=(f16)a[3];
  r[4]=(f16)b[0]; r[5]=(f16)b[1]; r[6]=(f16)b[2]; r[7]=(f16)b[3];
  return r;
}

// ---------------------------------------------------------------------------
// Repack W -> frag-major f16. Block bx = (p*32+kc)*4+nt, 64 threads.
// Softmax double-scale log2(e)/64 folded into Wq.
// ---------------------------------------------------------------------------
__global__ __launch_bounds__(64) void wrepack_kernel(
    const float* __restrict__ Wqg, const float* __restrict__ Wkg,
    const float* __restrict__ Wvg, f16* __restrict__ Wf)
{
  const int bx = blockIdx.x;
  const int nt = bx & 3;
  const int kc = (bx >> 2) & 31;
  const int p  = bx >> 7;
  const float* W = (p == 0) ? Wqg : (p == 1) ? Wkg : Wvg;
  const float sc = (p == 0) ? (1.4426950408889634f / 64.0f) : 1.0f;

  const int lane = threadIdx.x;
  const int l16 = lane & 15, quad = lane >> 4;
  const float* src = W + (size_t)(nt * 16 + l16) * CC + kc * 32 + quad * 8;
  f32x4 a = *(const f32x4*)src;
  f32x4 b = *(const f32x4*)(src + 4);
  f16x8 r;
  #pragma unroll
  for (int j = 0; j < 4; ++j) { r[j] = (f16)(a[j] * sc); r[j + 4] = (f16)(b[j] * sc); }
  *(f16x8*)(Wf + (size_t)bx * 512 + lane * 8) = r;
}

// ---------------------------------------------------------------------------
// Projection: X[16384,1024] fp32 x W^T -> frag-major f16.
// T3+T4 structure (counted vmcnt, never 0 in the main loop): 4 LDS stage
// buffers, prefetch depth 2, uniform 3 global_load_lds per wave per K-chunk
// (2x X rows + 1x W frag chunk). Per iter: issue(s+2) -> s_waitcnt vmcnt(6)
// (leaves stages s+1,s+2 in flight ACROSS the barrier) -> lgkmcnt(0) ->
// raw s_barrier -> compute(s). Slot-reuse safety: readers of slot (s+2)&3
// finished (lgkmcnt(0)) before barrier_{s-1}; overwrite issues after it.
// The previous version's __syncthreads() drained vmcnt(0) every iteration,
// capping proj at ~1.3 TB/s (latency-bound); this keeps 6 loads/wave in
// flight permanently. 48 KB LDS -> 3 blocks/CU.
// X chunks XOR-swizzled (phys slot = logical ^ (row&7)) via pre-swizzled
// global source so A-frag ds_read_b128s spread across banks.
// ---------------------------------------------------------------------------
__global__ __launch_bounds__(256) void proj_kernel(
    const float* __restrict__ qg, const float* __restrict__ kg, const float* __restrict__ vg,
    const f16* __restrict__ Wf,
    f16* __restrict__ Qf, f16* __restrict__ Kf, f16* __restrict__ Vf)
{
  __shared__ float Xs[4][64][32];     // 32 KB: 4 stages x 64 rows x 128B
  __shared__ f16   Ws[4][4][64][8];   // 16 KB: 4 stages x 4 nt-chunks x 1KB

  const float* X; f16* O; const int p = blockIdx.y;
  if (p == 0)      { X = qg; O = Qf; }
  else if (p == 1) { X = kg; O = Kf; }
  else             { X = vg; O = Vf; }

  const int tid  = threadIdx.x;
  const int w    = tid >> 6;
  const int lane = tid & 63;
  const int quad = lane >> 4;
  const int l16  = lane & 15;
  const int r0   = blockIdx.x * 64;

  // X staging: wave w inst j covers rows w*16+j*8 .. +7.
  // Lane i -> row (i>>3), phys 16B slot (i&7); source slot = (i&7)^(i>>3)
  // so that phys slot k of row R holds logical slot k^(R&7).
  const int Rrow = w * 16 + (lane >> 3);
  const int lsl  = (lane & 7) ^ (lane >> 3);
  const float* Xsrc0 = X + (size_t)(r0 + Rrow) * CC + lsl * 4;
  const float* Xsrc1 = Xsrc0 + 8 * CC;   // rows +8, same slot permutation

  // W staging: wave w stages nt-chunk w of each K-chunk (1KB contiguous).
  const f16* Wfp  = Wf + (size_t)p * 128 * 512;
  const f16* Wsrc = Wfp + (size_t)w * 512 + lane * 8;

  f32x4 acc[4];
  #pragma unroll
  for (int nt = 0; nt < 4; ++nt) acc[nt] = (f32x4){0.f, 0.f, 0.f, 0.f};

  // A-frag read slots: logical {2q, 2q+1} of row l16 -> phys XOR (l16&7)
  const int p0 = (2 * quad) ^ (l16 & 7);   // p1 = p0 ^ 1 (only bit0 differs)

  auto issue = [&](int s) {
    const int sl = s & 3;
    gl_lds16(Xsrc0 + (size_t)s * 32, &Xs[sl][w * 16][0]);
    gl_lds16(Xsrc1 + (size_t)s * 32, &Xs[sl][w * 16 + 8][0]);
    gl_lds16(Wsrc + (size_t)s * 2048, &Ws[sl][w][0][0]);
  };

  issue(0);
  issue(1);

  #pragma unroll
  for (int s = 0; s < 32; ++s) {
    if (s < 30) {
      issue(s + 2);
      asm volatile("s_waitcnt vmcnt(6)" ::: "memory");
    } else if (s == 30) {
      asm volatile("s_waitcnt vmcnt(3)" ::: "memory");
    } else {
      asm volatile("s_waitcnt vmcnt(0)" ::: "memory");
    }
    asm volatile("s_waitcnt lgkmcnt(0)" ::: "memory");
    __builtin_amdgcn_s_barrier();

    const int sl = s & 3;
    f32x4 a0 = *(const f32x4*)&Xs[sl][w * 16 + l16][p0 * 4];
    f32x4 a1 = *(const f32x4*)&Xs[sl][w * 16 + l16][(p0 ^ 1) * 4];
    f16x8 af = pack2(a0, a1);
    #pragma unroll
    for (int nt = 0; nt < 4; ++nt) {
      f16x8 bf = *(const f16x8*)&Ws[sl][nt][lane][0];
      acc[nt] = MFMA32(af, bf, acc[nt]);
    }
  }

  __syncthreads();   // all staging done; Xs free for epilogue scratch

  // epilogue: C-layout acc -> frag-major via wave-private LDS scratch (8KB/wave).
  f16 (*Ls)[66] = (f16(*)[66])((f16*)&Xs[0][0][0] + (size_t)w * 4096);
  #pragma unroll
  for (int nt = 0; nt < 4; ++nt)
    #pragma unroll
    for (int r = 0; r < 4; ++r)
      Ls[quad * 4 + r][nt * 16 + l16] = (f16)acc[nt][r];
  const size_t chunk = (size_t)blockIdx.x * 4 + w;
  if (p < 2) {
    // Q/K frag: [chunk][half][lane][8] = tile[row=l16][hd=32h+8q+j]
    #pragma unroll
    for (int h = 0; h < 2; ++h) {
      f16x8 t = *(const f16x8*)&Ls[l16][h * 32 + quad * 8];
      *(f16x8*)(O + (chunk * 2 + h) * 512 + lane * 8) = t;
    }
  } else {
    // V frag: [chunk][np][lane][8] = tile[key=4q+(j&3)][hd=(2np+(j>>2))*16+l16]
    #pragma unroll
    for (int np = 0; np < 2; ++np) {
      f16x8 t;
      #pragma unroll
      for (int j = 0; j < 8; ++j)
        t[j] = Ls[quad * 4 + (j & 3)][(2 * np + (j >> 2)) * 16 + l16];
      *(f16x8*)(O + (chunk * 2 + np) * 512 + lane * 8) = t;
    }
  }
}

// ---------------------------------------------------------------------------
// Flash attention, mask s <= t+1. Block-wide double-buffered async staging of
// K and V steps (each step = contiguous 8 KB in frag-major layout). Frag reads
// are lane-linear ds_read_b128 (conflict-free). Uniform trip counts.
// S^T via MFMA(A=K,B=Q); P C-layout == MFMA16 A-layout. Scale folded into Wq.
// ---------------------------------------------------------------------------
__device__ __forceinline__ void attn_tile(
    int b, int j, int a, int e, int wave, int quad, int l16, int lane, int sp,
    const f16* __restrict__ Qf, const f16* __restrict__ Kf, const f16* __restrict__ Vf,
    f16 (*Ks)[8][64][8], f16 (*Vs)[8][64][8],
    float* __restrict__ Opart, float* __restrict__ lpart)
{
  const int m0 = j * 64 + wave * 16;

  const f16* Kfb = Kf + (size_t)b * PB_F16;
  const f16* Vfb = Vf + (size_t)b * PB_F16;
  const f16* Qfb = Qf + (size_t)b * PB_F16;

  f16x8 qa0 = *(const f16x8*)(Qfb + ((size_t)(m0 >> 4) * 2 + 0) * 512 + lane * 8);
  f16x8 qa1 = *(const f16x8*)(Qfb + ((size_t)(m0 >> 4) * 2 + 1) * 512 + lane * 8);

  f32x4 o[4];
  float lsum = 0.f;
  #pragma unroll
  for (int nt = 0; nt < 4; ++nt) o[nt] = (f32x4){0.f, 0.f, 0.f, 0.f};

  // protect staging buffers from the previous tile's laggard readers
  __syncthreads();

  if (a < e) {
    #pragma unroll
    for (int jj = 0; jj < 2; ++jj) {
      const int idx = 2 * wave + jj;
      gl_lds16(Kfb + (size_t)a * 4096 + idx * 512 + lane * 8, &Ks[0][idx][0][0]);
      gl_lds16(Vfb + (size_t)a * 4096 + idx * 512 + lane * 8, &Vs[0][idx][0][0]);
    }
  }

  for (int st = a; st < e; ++st) {
    const int buf = (st - a) & 1;
    __syncthreads();   // drains staging of buf
    if (st + 1 < e) {
      #pragma unroll
      for (int jj = 0; jj < 2; ++jj) {
        const int idx = 2 * wave + jj;
        gl_lds16(Kfb + (size_t)(st + 1) * 4096 + idx * 512 + lane * 8, &Ks[buf ^ 1][idx][0][0]);
        gl_lds16(Vfb + (size_t)(st + 1) * 4096 + idx * 512 + lane * 8, &Vs[buf ^ 1][idx][0][0]);
      }
    }
    const int s0 = st * 64;

    // S^T = K Q^T (scale pre-folded into Q)
    f32x4 sc[4];
    #pragma unroll
    for (int ct = 0; ct < 4; ++ct) {
      f16x8 k0 = *(const f16x8*)&Ks[buf][ct * 2][lane][0];
      f16x8 k1 = *(const f16x8*)&Ks[buf][ct * 2 + 1][lane][0];
      f32x4 z = (f32x4){0.f, 0.f, 0.f, 0.f};
      z = MFMA32(k0, qa0, z);
      sc[ct] = MFMA32(k1, qa1, z);
    }

    // mask + exp2; lane: query=m0+l16, key=s0+ct*16+quad*4+r
    const bool domask = (s0 + 63) > (m0 + 1);
    f16x4 pa[4];
    #pragma unroll
    for (int ct = 0; ct < 4; ++ct) {
      #pragma unroll
      for (int r = 0; r < 4; ++r) {
        float x = sc[ct][r];
        if (domask) {
          const int key = s0 + ct * 16 + quad * 4 + r;
          if (key > m0 + l16 + 1) x = -__builtin_inff();
        }
        const float pv = __builtin_amdgcn_exp2f(x);
        lsum += pv;
        pa[ct][r] = (f16)pv;
      }
    }

    // PV: A=P (MFMA16 A-layout), B=V frag halves
    #pragma unroll
    for (int ct = 0; ct < 4; ++ct) {
      #pragma unroll
      for (int np = 0; np < 2; ++np) {
        f16x8 vv = *(const f16x8*)&Vs[buf][ct * 2 + np][lane][0];
        f16x4 blo = __builtin_shufflevector(vv, vv, 0, 1, 2, 3);
        f16x4 bhi = __builtin_shufflevector(vv, vv, 4, 5, 6, 7);
        o[2 * np]     = MFMA16(pa[ct], blo, o[2 * np]);
        o[2 * np + 1] = MFMA16(pa[ct], bhi, o[2 * np + 1]);
      }
    }
  }

  lsum += __shfl_xor(lsum, 16, 64);
  lsum += __shfl_xor(lsum, 32, 64);
  const size_t rbase = (size_t)(sp * BB + b) * TT;
  if (quad == 0) lpart[rbase + m0 + l16] = lsum;
  #pragma unroll
  for (int nt = 0; nt < 4; ++nt)
    #pragma unroll
    for (int r = 0; r < 4; ++r)
      Opart[(rbase + m0 + quad * 4 + r) * HH + nt * 16 + l16] = o[nt][r];
}

__global__ __launch_bounds__(256) void attn_kernel(
    const f16* __restrict__ Qf, const f16* __restrict__ Kf, const f16* __restrict__ Vf,
    float* __restrict__ Opart, float* __restrict__ lpart, int S)
{
  __shared__ f16 Ks[2][8][64][8];   // 16 KB
  __shared__ f16 Vs[2][8][64][8];   // 16 KB

  const int pr = blockIdx.x;
  const int sp = blockIdx.y;
  const int b  = blockIdx.z;
  const int tid  = threadIdx.x;
  const int wave = tid >> 6;
  const int lane = tid & 63;
  const int quad = lane >> 4;
  const int l16  = lane & 15;

  const int j1 = pr, j2 = 63 - pr;
  const int n1 = min(j1 + 2, 64), n2 = min(j2 + 2, 64);
  const int tot = n1 + n2;
  const int lo = tot * sp / S, hi = tot * (sp + 1) / S;
  const int a1 = min(lo, n1), e1 = min(hi, n1);
  const int a2 = max(lo - n1, 0), e2 = max(hi - n1, 0);

  attn_tile(b, j1, a1, e1, wave, quad, l16, lane, sp, Qf, Kf, Vf, Ks, Vs, Opart, lpart);
  attn_tile(b, j2, a2, e2, wave, quad, l16, lane, sp, Qf, Kf, Vf, Ks, Vs, Opart, lpart);
}

// ---------------------------------------------------------------------------
// Combine S split partials: out = sum_s O_s / sum_s l_s
// ---------------------------------------------------------------------------
__global__ __launch_bounds__(256) void combine_kernel(
    const float* __restrict__ Opart, const float* __restrict__ lpart,
    float* __restrict__ out, int S)
{
  const int idx = blockIdx.x * 256 + threadIdx.x;
  const int row = idx >> 4;
  const int c   = (idx & 15) * 4;
  float l = 0.f;
  f32x4 s = (f32x4){0.f, 0.f, 0.f, 0.f};
  for (int p = 0; p < S; ++p) {
    l += lpart[(size_t)p * BB * TT + row];
    s += *(const f32x4*)&Opart[((size_t)p * BB * TT + row) * HH + c];
  }
  const float inv = 1.0f / l;
  *(f32x4*)&out[(size_t)row * HH + c] = s * inv;
}

// ---------------------------------------------------------------------------
extern "C" void kernel_launch(void* const* d_in, const int* in_sizes, int n_in,
                              void* d_out, int out_size, void* d_ws, size_t ws_size,
                              hipStream_t stream)
{
  const float* q  = (const float*)d_in[0];
  const float* k  = (const float*)d_in[1];
  const float* v  = (const float*)d_in[2];
  const float* Wq = (const float*)d_in[3];
  const float* Wk = (const float*)d_in[4];
  const float* Wv = (const float*)d_in[5];
  float* out = (float*)d_out;

  const size_t n = (size_t)BB * TT * HH;   // 1,048,576 f16 per tensor
  const size_t need8 = (WF_ELEMS + 3 * n) * sizeof(f16)
                     + 8 * n * sizeof(float) + 8 * (size_t)BB * TT * sizeof(float);
  const int S = (ws_size >= need8) ? 8 : 4;

  f16* Wf = (f16*)d_ws;
  f16* Qf = Wf + WF_ELEMS;
  f16* Kf = Qf + n;
  f16* Vf = Kf + n;
  float* Opart = (float*)(Vf + n);
  float* lpart = Opart + (size_t)S * n;

  wrepack_kernel<<<dim3(384), 64, 0, stream>>>(Wq, Wk, Wv, Wf);
  proj_kernel<<<dim3(256, 3), 256, 0, stream>>>(q, k, v, Wf, Qf, Kf, Vf);
  attn_kernel<<<dim3(32, S, BB), 256, 0, stream>>>(Qf, Kf, Vf, Opart, lpart, S);
  combine_kernel<<<dim3(1024), 256, 0, stream>>>(Opart, lpart, out, S);
}